// Round 1
// baseline (1290.171 us; speedup 1.0000x reference)
//
#include <hip/hip_runtime.h>
#include <math.h>

#define NB 8192
#define DD 512
#define HH 256
#define NSPLIT 32
#define JSPAN (NB / NSPLIT)   // 256 columns per split
#define BK 32
#define LS 132                // padded k-major LDS row stride (floats), 16B-aligned rows

__device__ __forceinline__ bool better(float v1, int j1, float v2, int j2) {
    return (v1 > v2) || (v1 == v2 && j1 < j2);
}

// ---------------- Kernel 1: fused MLP  proj = relu(sess@W1+b1)@W2+b2 ----------------
__global__ __launch_bounds__(256)
void mlp_kernel(const float* __restrict__ sess, const float* __restrict__ W1,
                const float* __restrict__ b1, const float* __restrict__ W2,
                const float* __restrict__ b2, float* __restrict__ proj) {
    __shared__ float srow[8][DD];   // 16 KB
    __shared__ float sh[8][HH];     // 8 KB
    const int t = threadIdx.x;      // 256
    const int r0 = blockIdx.x * 8;

    // stage 8 input rows (coalesced float4)
    const float4* src = (const float4*)(sess + (size_t)r0 * DD);
    float4* dst = (float4*)&srow[0][0];
#pragma unroll
    for (int i = 0; i < 4; ++i) dst[t + i * 256] = src[t + i * 256];
    __syncthreads();

    // h[:, t]
    float acc[8];
#pragma unroll
    for (int r = 0; r < 8; ++r) acc[r] = b1[t];
    for (int k = 0; k < DD; ++k) {
        float w = W1[k * HH + t];
#pragma unroll
        for (int r = 0; r < 8; ++r) acc[r] = fmaf(srow[r][k], w, acc[r]);
    }
#pragma unroll
    for (int r = 0; r < 8; ++r) sh[r][t] = fmaxf(acc[r], 0.f);
    __syncthreads();

    // proj[:, t] and proj[:, t+256]
    float a0[8], a1[8];
#pragma unroll
    for (int r = 0; r < 8; ++r) { a0[r] = b2[t]; a1[r] = b2[t + 256]; }
    for (int k = 0; k < HH; ++k) {
        float w0 = W2[k * DD + t];
        float w1 = W2[k * DD + t + 256];
#pragma unroll
        for (int r = 0; r < 8; ++r) {
            float hv = sh[r][k];
            a0[r] = fmaf(hv, w0, a0[r]);
            a1[r] = fmaf(hv, w1, a1[r]);
        }
    }
#pragma unroll
    for (int r = 0; r < 8; ++r) {
        proj[(size_t)(r0 + r) * DD + t] = a0[r];
        proj[(size_t)(r0 + r) * DD + t + 256] = a1[r];
    }
}

// ------------- Kernel 2: sim = proj@proj.T with fused online top-3 per row -------------
// grid: (64 row-tiles of 128, NSPLIT j-splits of 256). 256 thr, 8x8 reg tile -> 128x128 C.
__global__ __launch_bounds__(256)
void sim_topk_kernel(const float* __restrict__ proj,
                     float* __restrict__ pvals, int* __restrict__ pidx) {
    __shared__ float As[BK][LS];
    __shared__ float Bs[BK][LS];
    const int t = threadIdx.x;
    const int tx = t & 15, ty = t >> 4;
    const int rb = blockIdx.x * 128;
    const int jb0 = blockIdx.y * JSPAN;

    float tv0[8], tv1[8], tv2[8];
    int tj0[8], tj1[8], tj2[8];
#pragma unroll
    for (int i = 0; i < 8; ++i) { tv0[i] = tv1[i] = tv2[i] = -INFINITY; tj0[i] = tj1[i] = tj2[i] = 0; }

    for (int nt = 0; nt < 2; ++nt) {
        const int jb = jb0 + nt * 128;
        float acc[8][8];
#pragma unroll
        for (int i = 0; i < 8; ++i)
#pragma unroll
            for (int j = 0; j < 8; ++j) acc[i][j] = 0.f;

        for (int k0 = 0; k0 < DD; k0 += BK) {
            __syncthreads();   // protect LDS from previous iteration's readers
#pragma unroll
            for (int i = 0; i < 4; ++i) {
                int f = t + i * 256;          // 0..1023
                int row = f >> 3;
                int kq = (f & 7) << 2;
                float4 va = *(const float4*)&proj[(size_t)(rb + row) * DD + k0 + kq];
                As[kq + 0][row] = va.x; As[kq + 1][row] = va.y;
                As[kq + 2][row] = va.z; As[kq + 3][row] = va.w;
                float4 vb = *(const float4*)&proj[(size_t)(jb + row) * DD + k0 + kq];
                Bs[kq + 0][row] = vb.x; Bs[kq + 1][row] = vb.y;
                Bs[kq + 2][row] = vb.z; Bs[kq + 3][row] = vb.w;
            }
            __syncthreads();
#pragma unroll
            for (int kk = 0; kk < BK; ++kk) {
                float4 va0 = *(const float4*)&As[kk][4 * ty];
                float4 va1 = *(const float4*)&As[kk][64 + 4 * ty];
                float4 vb0 = *(const float4*)&Bs[kk][4 * tx];
                float4 vb1 = *(const float4*)&Bs[kk][64 + 4 * tx];
                float a[8] = {va0.x, va0.y, va0.z, va0.w, va1.x, va1.y, va1.z, va1.w};
                float b[8] = {vb0.x, vb0.y, vb0.z, vb0.w, vb1.x, vb1.y, vb1.z, vb1.w};
#pragma unroll
                for (int i = 0; i < 8; ++i)
#pragma unroll
                    for (int j = 0; j < 8; ++j)
                        acc[i][j] = fmaf(a[i], b[j], acc[i][j]);
            }
        }
        // fold this 128-col tile into the running per-thread top-3 (ascending j order)
#pragma unroll
        for (int i = 0; i < 8; ++i) {
#pragma unroll
            for (int j = 0; j < 8; ++j) {
                int jg = jb + ((j < 4) ? (4 * tx + j) : (64 + 4 * tx + (j - 4)));
                float v = acc[i][j];
                if (v > tv2[i]) {
                    if (v > tv1[i]) {
                        if (v > tv0[i]) {
                            tv2[i] = tv1[i]; tj2[i] = tj1[i];
                            tv1[i] = tv0[i]; tj1[i] = tj0[i];
                            tv0[i] = v; tj0[i] = jg;
                        } else {
                            tv2[i] = tv1[i]; tj2[i] = tj1[i];
                            tv1[i] = v; tj1[i] = jg;
                        }
                    } else { tv2[i] = v; tj2[i] = jg; }
                }
            }
        }
    }

    // butterfly merge across the 16 tx-lanes sharing each row
#pragma unroll
    for (int i = 0; i < 8; ++i) {
        float av0 = tv0[i], av1 = tv1[i], av2 = tv2[i];
        int aj0 = tj0[i], aj1 = tj1[i], aj2 = tj2[i];
#pragma unroll
        for (int s = 1; s < 16; s <<= 1) {
            float bv0 = __shfl_xor(av0, s, 64), bv1 = __shfl_xor(av1, s, 64), bv2 = __shfl_xor(av2, s, 64);
            int bj0 = __shfl_xor(aj0, s, 64), bj1 = __shfl_xor(aj1, s, 64), bj2 = __shfl_xor(aj2, s, 64);
            bool c0 = better(av0, aj0, bv0, bj0);
            float r0v = c0 ? av0 : bv0; int r0j = c0 ? aj0 : bj0;
            bool c1 = c0 ? better(av1, aj1, bv0, bj0) : better(av0, aj0, bv1, bj1);
            float r1v = c0 ? (c1 ? av1 : bv0) : (c1 ? av0 : bv1);
            int   r1j = c0 ? (c1 ? aj1 : bj0) : (c1 ? aj0 : bj1);
            int na = (int)c0 + (int)c1;
            float cav = (na == 2) ? av2 : ((na == 1) ? av1 : av0);
            int   caj = (na == 2) ? aj2 : ((na == 1) ? aj1 : aj0);
            float cbv = (na == 2) ? bv0 : ((na == 1) ? bv1 : bv2);
            int   cbj = (na == 2) ? bj0 : ((na == 1) ? bj1 : bj2);
            bool c2 = better(cav, caj, cbv, cbj);
            av0 = r0v; aj0 = r0j; av1 = r1v; aj1 = r1j;
            av2 = c2 ? cav : cbv; aj2 = c2 ? caj : cbj;
        }
        if (tx == 0) {
            int row = rb + ((i < 4) ? (4 * ty + i) : (64 + 4 * ty + (i - 4)));
            size_t base = ((size_t)row * NSPLIT + blockIdx.y) * 3;
            pvals[base + 0] = av0; pvals[base + 1] = av1; pvals[base + 2] = av2;
            pidx[base + 0] = aj0; pidx[base + 1] = aj1; pidx[base + 2] = aj2;
        }
    }
}

// ------------- Kernel 3: merge 32 partial top-3s -> top-6 candidate indices -------------
__global__ __launch_bounds__(256)
void merge_kernel(const float* __restrict__ pvals, const int* __restrict__ pidx,
                  int* __restrict__ cand) {
    int r = blockIdx.x * 256 + threadIdx.x;
    if (r >= NB) return;
    float v0 = -INFINITY, v1 = -INFINITY, v2 = -INFINITY, v3 = -INFINITY, v4 = -INFINITY, v5 = -INFINITY;
    int j0 = 0, j1 = 0, j2 = 0, j3 = 0, j4 = 0, j5 = 0;
    const float* pv = pvals + (size_t)r * NSPLIT * 3;
    const int* pj = pidx + (size_t)r * NSPLIT * 3;
    for (int s = 0; s < NSPLIT * 3; ++s) {
        float v = pv[s]; int j = pj[s];
        if (v > v5) {
            if (v > v2) {
                if (v > v1) {
                    if (v > v0) { v5=v4;j5=j4; v4=v3;j4=j3; v3=v2;j3=j2; v2=v1;j2=j1; v1=v0;j1=j0; v0=v;j0=j; }
                    else       { v5=v4;j5=j4; v4=v3;j4=j3; v3=v2;j3=j2; v2=v1;j2=j1; v1=v;j1=j; }
                } else         { v5=v4;j5=j4; v4=v3;j4=j3; v3=v2;j3=j2; v2=v;j2=j; }
            } else {
                if (v > v4) {
                    if (v > v3) { v5=v4;j5=j4; v4=v3;j4=j3; v3=v;j3=j; }
                    else        { v5=v4;j5=j4; v4=v;j4=j; }
                } else          { v5=v;j5=j; }
            }
        }
    }
    int* c = cand + (size_t)r * 6;
    c[0] = j0; c[1] = j1; c[2] = j2; c[3] = j3; c[4] = j4; c[5] = j5;
}

// --------- Kernel 3b: exact fp64 re-rank of 6 candidates + softmax weights ---------
__global__ __launch_bounds__(64)
void rerank_kernel(const float* __restrict__ proj, const int* __restrict__ cand,
                   int* __restrict__ widx, float* __restrict__ wts,
                   float* __restrict__ cos_out) {
    int r = blockIdx.x;
    int t = threadIdx.x;     // 64 lanes = 1 wave
    const float* pr = proj + (size_t)r * DD;
    int c[6];
#pragma unroll
    for (int i = 0; i < 6; ++i) c[i] = cand[(size_t)r * 6 + i];
    float myp[8];
#pragma unroll
    for (int k = 0; k < 8; ++k) myp[k] = pr[t * 8 + k];
    double part[6];
#pragma unroll
    for (int i = 0; i < 6; ++i) {
        const float* pc = proj + (size_t)c[i] * DD;
        double s = 0.0;
#pragma unroll
        for (int k = 0; k < 8; ++k) s += (double)myp[k] * (double)pc[t * 8 + k];
        part[i] = s;
    }
#pragma unroll
    for (int i = 0; i < 6; ++i) {
#pragma unroll
        for (int s = 1; s < 64; s <<= 1) part[i] += __shfl_xor(part[i], s, 64);
    }
    if (t == 0) {
        double bv0 = -1e300, bv1 = -1e300, bv2 = -1e300;
        int bj0 = 0x7fffffff, bj1 = 0x7fffffff, bj2 = 0x7fffffff;
#pragma unroll
        for (int i = 0; i < 6; ++i) {
            double v = part[i]; int j = c[i];
            bool g2 = (v > bv2) || (v == bv2 && j < bj2);
            bool g1 = (v > bv1) || (v == bv1 && j < bj1);
            bool g0 = (v > bv0) || (v == bv0 && j < bj0);
            if (g2) {
                if (g1) {
                    if (g0) { bv2 = bv1; bj2 = bj1; bv1 = bv0; bj1 = bj0; bv0 = v; bj0 = j; }
                    else    { bv2 = bv1; bj2 = bj1; bv1 = v; bj1 = j; }
                } else      { bv2 = v; bj2 = j; }
            }
        }
        double e0 = exp(bv0 - bv0), e1 = exp(bv1 - bv0), e2 = exp(bv2 - bv0);
        double inv = 1.0 / (e0 + e1 + e2);
        float w0 = (float)(e0 * inv), w1 = (float)(e1 * inv), w2 = (float)(e2 * inv);
        widx[r * 3 + 0] = bj0; widx[r * 3 + 1] = bj1; widx[r * 3 + 2] = bj2;
        wts[r * 3 + 0] = w0; wts[r * 3 + 1] = w1; wts[r * 3 + 2] = w2;
        cos_out[r * 3 + 0] = w0; cos_out[r * 3 + 1] = w1; cos_out[r * 3 + 2] = w2;
    }
}

// ---------------- Kernel 4: gather sess_topk + weighted neighbor_sess ----------------
__global__ __launch_bounds__(128)
void out_kernel(const float* __restrict__ sess, const int* __restrict__ widx,
                const float* __restrict__ wts, float* __restrict__ out) {
    int b = blockIdx.x;
    int t = threadIdx.x;   // 128 -> one float4 per thread per row
    int i0 = widx[b * 3 + 0], i1 = widx[b * 3 + 1], i2 = widx[b * 3 + 2];
    float w0 = wts[b * 3 + 0], w1 = wts[b * 3 + 1], w2 = wts[b * 3 + 2];
    const float4* s0 = (const float4*)(sess + (size_t)i0 * DD);
    const float4* s1 = (const float4*)(sess + (size_t)i1 * DD);
    const float4* s2 = (const float4*)(sess + (size_t)i2 * DD);
    float4 x0 = s0[t], x1 = s1[t], x2 = s2[t];
    float4* o = (float4*)(out + (size_t)b * 3 * DD);
    o[t] = x0; o[128 + t] = x1; o[256 + t] = x2;
    float4 nbv;
    nbv.x = fmaf(w0, x0.x, fmaf(w1, x1.x, w2 * x2.x));
    nbv.y = fmaf(w0, x0.y, fmaf(w1, x1.y, w2 * x2.y));
    nbv.z = fmaf(w0, x0.z, fmaf(w1, x1.z, w2 * x2.z));
    nbv.w = fmaf(w0, x0.w, fmaf(w1, x1.w, w2 * x2.w));
    ((float4*)(out + (size_t)NB * 3 * DD + (size_t)b * DD))[t] = nbv;
}

extern "C" void kernel_launch(void* const* d_in, const int* in_sizes, int n_in,
                              void* d_out, int out_size, void* d_ws, size_t ws_size,
                              hipStream_t stream) {
    const float* sess = (const float*)d_in[0];
    // d_in[1] = pool_emb: unused by the reference
    const float* W1 = (const float*)d_in[2];
    const float* b1 = (const float*)d_in[3];
    const float* W2 = (const float*)d_in[4];
    const float* b2 = (const float*)d_in[5];
    float* out = (float*)d_out;

    float* proj  = (float*)d_ws;                            // NB*DD f32
    float* pvals = proj + (size_t)NB * DD;                  // NB*NSPLIT*3 f32
    int*   pidx  = (int*)(pvals + (size_t)NB * NSPLIT * 3); // NB*NSPLIT*3 i32
    int*   cand  = pidx + (size_t)NB * NSPLIT * 3;          // NB*6 i32
    int*   widx  = cand + (size_t)NB * 6;                   // NB*3 i32
    float* wts   = (float*)(widx + (size_t)NB * 3);         // NB*3 f32

    float* cos_out = out + (size_t)NB * 3 * DD + (size_t)NB * DD;

    hipLaunchKernelGGL(mlp_kernel, dim3(NB / 8), dim3(256), 0, stream, sess, W1, b1, W2, b2, proj);
    hipLaunchKernelGGL(sim_topk_kernel, dim3(64, NSPLIT), dim3(256), 0, stream, proj, pvals, pidx);
    hipLaunchKernelGGL(merge_kernel, dim3(NB / 256), dim3(256), 0, stream, pvals, pidx, cand);
    hipLaunchKernelGGL(rerank_kernel, dim3(NB), dim3(64), 0, stream, proj, cand, widx, wts, cos_out);
    hipLaunchKernelGGL(out_kernel, dim3(NB), dim3(128), 0, stream, sess, widx, wts, out);
}

// Round 2
// 473.218 us; speedup vs baseline: 2.7264x; 2.7264x over previous
//
#include <hip/hip_runtime.h>
#include <hip/hip_bf16.h>
#include <math.h>

#define NB 8192
#define DD 512
#define HH 256
#define NCT 64            // 64 column tiles of 128
#define NCAND 8

typedef __attribute__((ext_vector_type(8))) short bf16x8;
typedef __attribute__((ext_vector_type(4))) float f32x4;

#define AS1(p) ((const __attribute__((address_space(1))) void*)(p))
#define AS3(p) ((__attribute__((address_space(3))) void*)(p))

__device__ __forceinline__ bool better(float v1, int j1, float v2, int j2) {
    return (v1 > v2) || (v1 == v2 && j1 < j2);
}

// ---------------- Kernel 1: fused MLP  proj = relu(sess@W1+b1)@W2+b2 (+ bf16 copy) ----------------
__global__ __launch_bounds__(256)
void mlp_kernel(const float* __restrict__ sess, const float* __restrict__ W1,
                const float* __restrict__ b1, const float* __restrict__ W2,
                const float* __restrict__ b2, float* __restrict__ proj,
                __hip_bfloat16* __restrict__ projb) {
    __shared__ float srow[8][DD];   // 16 KB
    __shared__ float sh[8][HH];     // 8 KB
    const int t = threadIdx.x;      // 256
    const int r0 = blockIdx.x * 8;

    const float4* src = (const float4*)(sess + (size_t)r0 * DD);
    float4* dst = (float4*)&srow[0][0];
#pragma unroll
    for (int i = 0; i < 4; ++i) dst[t + i * 256] = src[t + i * 256];
    __syncthreads();

    float acc[8];
#pragma unroll
    for (int r = 0; r < 8; ++r) acc[r] = b1[t];
    for (int k = 0; k < DD; ++k) {
        float w = W1[k * HH + t];
#pragma unroll
        for (int r = 0; r < 8; ++r) acc[r] = fmaf(srow[r][k], w, acc[r]);
    }
#pragma unroll
    for (int r = 0; r < 8; ++r) sh[r][t] = fmaxf(acc[r], 0.f);
    __syncthreads();

    float a0[8], a1[8];
#pragma unroll
    for (int r = 0; r < 8; ++r) { a0[r] = b2[t]; a1[r] = b2[t + 256]; }
    for (int k = 0; k < HH; ++k) {
        float w0 = W2[k * DD + t];
        float w1 = W2[k * DD + t + 256];
#pragma unroll
        for (int r = 0; r < 8; ++r) {
            float hv = sh[r][k];
            a0[r] = fmaf(hv, w0, a0[r]);
            a1[r] = fmaf(hv, w1, a1[r]);
        }
    }
#pragma unroll
    for (int r = 0; r < 8; ++r) {
        size_t i0 = (size_t)(r0 + r) * DD + t;
        size_t i1 = i0 + 256;
        proj[i0] = a0[r];
        proj[i1] = a1[r];
        projb[i0] = __float2bfloat16(a0[r]);
        projb[i1] = __float2bfloat16(a1[r]);
    }
}

// ------------- Kernel 2: bf16 MFMA sim tile (128x128) with fused top-3 epilogue -------------
// grid (64 row-tiles, 64 col-tiles), 256 thr = 4 waves (2x2 of 64x64), 16x16x32 bf16 MFMA.
__global__ __launch_bounds__(256)
void sim_mfma_kernel(const short* __restrict__ projb,
                     float* __restrict__ pvals, int* __restrict__ pidx) {
    __shared__ short As[128 * 32];   // 8 KB, row-major [128][32] bf16
    __shared__ short Bs[128 * 32];   // 8 KB
    __shared__ float evals[128][6];  // 3 KB
    __shared__ int   eidx[128][6];   // 3 KB

    const int t = threadIdx.x;
    const int w = t >> 6, l = t & 63;
    const int wr = w >> 1, wc = w & 1;
    const int tx = l & 15, tg = l >> 4;
    const int rb = blockIdx.x * 128;
    const int jb = blockIdx.y * 128;

    f32x4 acc[4][4];
#pragma unroll
    for (int i = 0; i < 4; ++i)
#pragma unroll
        for (int j = 0; j < 4; ++j) acc[i][j] = (f32x4){0.f, 0.f, 0.f, 0.f};

    // staging geometry: per wave 2 chunks of 1024B per tile; lane l covers 16B
    const int chunkA = w * 2;                 // chunks 0..7 over the two instrs
    const int srowA0 = chunkA * 16 + (l >> 2); // row for q=0
    const int scol = (l & 3) * 8;             // short offset within row

    for (int k0 = 0; k0 < DD; k0 += 32) {
        __syncthreads();   // protect LDS from previous iteration's readers
#pragma unroll
        for (int q = 0; q < 2; ++q) {
            int row = srowA0 + q * 16;
            const short* ga = projb + (size_t)(rb + row) * DD + k0 + scol;
            __builtin_amdgcn_global_load_lds(AS1(ga), AS3(As + (chunkA + q) * 512), 16, 0, 0);
            const short* gb = projb + (size_t)(jb + row) * DD + k0 + scol;
            __builtin_amdgcn_global_load_lds(AS1(gb), AS3(Bs + (chunkA + q) * 512), 16, 0, 0);
        }
        __syncthreads();   // drains vmcnt (global_load_lds) before ds_read

        bf16x8 af[4], bf[4];
#pragma unroll
        for (int mi = 0; mi < 4; ++mi)
            af[mi] = *(const bf16x8*)&As[(wr * 64 + mi * 16 + tx) * 32 + tg * 8];
#pragma unroll
        for (int nj = 0; nj < 4; ++nj)
            bf[nj] = *(const bf16x8*)&Bs[(wc * 64 + nj * 16 + tx) * 32 + tg * 8];
#pragma unroll
        for (int mi = 0; mi < 4; ++mi)
#pragma unroll
            for (int nj = 0; nj < 4; ++nj)
                acc[mi][nj] = __builtin_amdgcn_mfma_f32_16x16x32_bf16(af[mi], bf[nj], acc[mi][nj], 0, 0, 0);
    }

    // ---- fused top-3 epilogue ----
    // C/D layout: within frag (mi,nj): row = mi*16 + tg*4 + r, col = nj*16 + tx (verified m89/m91)
#pragma unroll
    for (int mi = 0; mi < 4; ++mi) {
#pragma unroll
        for (int r = 0; r < 4; ++r) {
            float v0 = -INFINITY, v1 = -INFINITY, v2 = -INFINITY;
            int j0 = 0, j1 = 0, j2 = 0;
#pragma unroll
            for (int nj = 0; nj < 4; ++nj) {
                float v = acc[mi][nj][r];
                int jg = jb + wc * 64 + nj * 16 + tx;
                if (v > v2) {
                    if (v > v1) {
                        if (v > v0) { v2 = v1; j2 = j1; v1 = v0; j1 = j0; v0 = v; j0 = jg; }
                        else        { v2 = v1; j2 = j1; v1 = v; j1 = jg; }
                    } else { v2 = v; j2 = jg; }
                }
            }
            // butterfly over the 16 tx-lanes sharing this row
#pragma unroll
            for (int s = 1; s < 16; s <<= 1) {
                float bv0 = __shfl_xor(v0, s, 64), bv1 = __shfl_xor(v1, s, 64), bv2 = __shfl_xor(v2, s, 64);
                int bj0 = __shfl_xor(j0, s, 64), bj1 = __shfl_xor(j1, s, 64), bj2 = __shfl_xor(j2, s, 64);
                bool c0 = better(v0, j0, bv0, bj0);
                float r0v = c0 ? v0 : bv0; int r0j = c0 ? j0 : bj0;
                bool c1 = c0 ? better(v1, j1, bv0, bj0) : better(v0, j0, bv1, bj1);
                float r1v = c0 ? (c1 ? v1 : bv0) : (c1 ? v0 : bv1);
                int   r1j = c0 ? (c1 ? j1 : bj0) : (c1 ? j0 : bj1);
                int na = (int)c0 + (int)c1;
                float cav = (na == 2) ? v2 : ((na == 1) ? v1 : v0);
                int   caj = (na == 2) ? j2 : ((na == 1) ? j1 : j0);
                float cbv = (na == 2) ? bv0 : ((na == 1) ? bv1 : bv2);
                int   cbj = (na == 2) ? bj0 : ((na == 1) ? bj1 : bj2);
                bool c2 = better(cav, caj, cbv, cbj);
                v0 = r0v; j0 = r0j; v1 = r1v; j1 = r1j;
                v2 = c2 ? cav : cbv; j2 = c2 ? caj : cbj;
            }
            if (tx == 0) {
                int lrow = wr * 64 + mi * 16 + tg * 4 + r;
                evals[lrow][wc * 3 + 0] = v0; eidx[lrow][wc * 3 + 0] = j0;
                evals[lrow][wc * 3 + 1] = v1; eidx[lrow][wc * 3 + 1] = j1;
                evals[lrow][wc * 3 + 2] = v2; eidx[lrow][wc * 3 + 2] = j2;
            }
        }
    }
    __syncthreads();
    if (t < 128) {
        float v0 = -INFINITY, v1 = -INFINITY, v2 = -INFINITY;
        int j0 = 0, j1 = 0, j2 = 0;
#pragma unroll
        for (int s = 0; s < 6; ++s) {
            float v = evals[t][s]; int j = eidx[t][s];
            bool g2 = better(v, j, v2, j2);
            bool g1 = better(v, j, v1, j1);
            bool g0 = better(v, j, v0, j0);
            if (g2) {
                if (g1) {
                    if (g0) { v2 = v1; j2 = j1; v1 = v0; j1 = j0; v0 = v; j0 = j; }
                    else    { v2 = v1; j2 = j1; v1 = v; j1 = j; }
                } else      { v2 = v; j2 = j; }
            }
        }
        size_t base = ((size_t)(rb + t) * NCT + blockIdx.y) * 3;
        pvals[base + 0] = v0; pvals[base + 1] = v1; pvals[base + 2] = v2;
        pidx[base + 0] = j0; pidx[base + 1] = j1; pidx[base + 2] = j2;
    }
}

// ------------- Kernel 3: merge 64 partial top-3s -> top-8 candidate indices -------------
__global__ __launch_bounds__(256)
void merge_kernel(const float* __restrict__ pvals, const int* __restrict__ pidx,
                  int* __restrict__ cand) {
    int r = blockIdx.x * 256 + threadIdx.x;
    if (r >= NB) return;
    float bv[NCAND]; int bj[NCAND];
#pragma unroll
    for (int p = 0; p < NCAND; ++p) { bv[p] = -INFINITY; bj[p] = 0x7fffffff; }
    const float* pv = pvals + (size_t)r * NCT * 3;
    const int* pj = pidx + (size_t)r * NCT * 3;
    for (int s = 0; s < NCT * 3; ++s) {
        float v = pv[s]; int j = pj[s];
        if (!better(v, j, bv[NCAND - 1], bj[NCAND - 1])) continue;
#pragma unroll
        for (int p = NCAND - 1; p > 0; --p) {
            bool hp = better(v, j, bv[p], bj[p]);
            bool gp = better(v, j, bv[p - 1], bj[p - 1]);
            bv[p] = hp ? (gp ? bv[p - 1] : v) : bv[p];
            bj[p] = hp ? (gp ? bj[p - 1] : j) : bj[p];
        }
        bool h0 = better(v, j, bv[0], bj[0]);
        bv[0] = h0 ? v : bv[0];
        bj[0] = h0 ? j : bj[0];
    }
    int* c = cand + (size_t)r * NCAND;
#pragma unroll
    for (int p = 0; p < NCAND; ++p) c[p] = bj[p];
}

// --------- Kernel 3b: exact fp64 re-rank of 8 candidates + softmax weights ---------
__global__ __launch_bounds__(64)
void rerank_kernel(const float* __restrict__ proj, const int* __restrict__ cand,
                   int* __restrict__ widx, float* __restrict__ wts,
                   float* __restrict__ cos_out) {
    int r = blockIdx.x;
    int t = threadIdx.x;     // 64 lanes = 1 wave
    const float* pr = proj + (size_t)r * DD;
    int c[NCAND];
#pragma unroll
    for (int i = 0; i < NCAND; ++i) c[i] = cand[(size_t)r * NCAND + i];
    float myp[8];
#pragma unroll
    for (int k = 0; k < 8; ++k) myp[k] = pr[t * 8 + k];
    double part[NCAND];
#pragma unroll
    for (int i = 0; i < NCAND; ++i) {
        const float* pc = proj + (size_t)c[i] * DD;
        double s = 0.0;
#pragma unroll
        for (int k = 0; k < 8; ++k) s += (double)myp[k] * (double)pc[t * 8 + k];
        part[i] = s;
    }
#pragma unroll
    for (int i = 0; i < NCAND; ++i) {
#pragma unroll
        for (int s = 1; s < 64; s <<= 1) part[i] += __shfl_xor(part[i], s, 64);
    }
    if (t == 0) {
        double bv0 = -1e300, bv1 = -1e300, bv2 = -1e300;
        int bj0 = 0x7fffffff, bj1 = 0x7fffffff, bj2 = 0x7fffffff;
#pragma unroll
        for (int i = 0; i < NCAND; ++i) {
            double v = part[i]; int j = c[i];
            bool g2 = (v > bv2) || (v == bv2 && j < bj2);
            bool g1 = (v > bv1) || (v == bv1 && j < bj1);
            bool g0 = (v > bv0) || (v == bv0 && j < bj0);
            if (g2) {
                if (g1) {
                    if (g0) { bv2 = bv1; bj2 = bj1; bv1 = bv0; bj1 = bj0; bv0 = v; bj0 = j; }
                    else    { bv2 = bv1; bj2 = bj1; bv1 = v; bj1 = j; }
                } else      { bv2 = v; bj2 = j; }
            }
        }
        double e0 = exp(bv0 - bv0), e1 = exp(bv1 - bv0), e2 = exp(bv2 - bv0);
        double inv = 1.0 / (e0 + e1 + e2);
        float w0 = (float)(e0 * inv), w1 = (float)(e1 * inv), w2 = (float)(e2 * inv);
        widx[r * 3 + 0] = bj0; widx[r * 3 + 1] = bj1; widx[r * 3 + 2] = bj2;
        wts[r * 3 + 0] = w0; wts[r * 3 + 1] = w1; wts[r * 3 + 2] = w2;
        cos_out[r * 3 + 0] = w0; cos_out[r * 3 + 1] = w1; cos_out[r * 3 + 2] = w2;
    }
}

// ---------------- Kernel 4: gather sess_topk + weighted neighbor_sess ----------------
__global__ __launch_bounds__(128)
void out_kernel(const float* __restrict__ sess, const int* __restrict__ widx,
                const float* __restrict__ wts, float* __restrict__ out) {
    int b = blockIdx.x;
    int t = threadIdx.x;   // 128 -> one float4 per thread per row
    int i0 = widx[b * 3 + 0], i1 = widx[b * 3 + 1], i2 = widx[b * 3 + 2];
    float w0 = wts[b * 3 + 0], w1 = wts[b * 3 + 1], w2 = wts[b * 3 + 2];
    const float4* s0 = (const float4*)(sess + (size_t)i0 * DD);
    const float4* s1 = (const float4*)(sess + (size_t)i1 * DD);
    const float4* s2 = (const float4*)(sess + (size_t)i2 * DD);
    float4 x0 = s0[t], x1 = s1[t], x2 = s2[t];
    float4* o = (float4*)(out + (size_t)b * 3 * DD);
    o[t] = x0; o[128 + t] = x1; o[256 + t] = x2;
    float4 nbv;
    nbv.x = fmaf(w0, x0.x, fmaf(w1, x1.x, w2 * x2.x));
    nbv.y = fmaf(w0, x0.y, fmaf(w1, x1.y, w2 * x2.y));
    nbv.z = fmaf(w0, x0.z, fmaf(w1, x1.z, w2 * x2.z));
    nbv.w = fmaf(w0, x0.w, fmaf(w1, x1.w, w2 * x2.w));
    ((float4*)(out + (size_t)NB * 3 * DD + (size_t)b * DD))[t] = nbv;
}

extern "C" void kernel_launch(void* const* d_in, const int* in_sizes, int n_in,
                              void* d_out, int out_size, void* d_ws, size_t ws_size,
                              hipStream_t stream) {
    const float* sess = (const float*)d_in[0];
    // d_in[1] = pool_emb: unused by the reference
    const float* W1 = (const float*)d_in[2];
    const float* b1 = (const float*)d_in[3];
    const float* W2 = (const float*)d_in[4];
    const float* b2 = (const float*)d_in[5];
    float* out = (float*)d_out;

    float* proj = (float*)d_ws;                                    // NB*DD f32 (16 MB)
    __hip_bfloat16* projb = (__hip_bfloat16*)(proj + (size_t)NB * DD); // NB*DD bf16 (8 MB)
    float* pvals = (float*)((char*)projb + (size_t)NB * DD * 2);   // NB*NCT*3 f32 (6.3 MB)
    int*   pidx  = (int*)(pvals + (size_t)NB * NCT * 3);           // NB*NCT*3 i32 (6.3 MB)
    int*   cand  = pidx + (size_t)NB * NCT * 3;                    // NB*8 i32
    int*   widx  = cand + (size_t)NB * NCAND;                      // NB*3 i32
    float* wts   = (float*)(widx + (size_t)NB * 3);                // NB*3 f32

    float* cos_out = out + (size_t)NB * 3 * DD + (size_t)NB * DD;

    hipLaunchKernelGGL(mlp_kernel, dim3(NB / 8), dim3(256), 0, stream, sess, W1, b1, W2, b2, proj, projb);
    hipLaunchKernelGGL(sim_mfma_kernel, dim3(64, 64), dim3(256), 0, stream, (const short*)projb, pvals, pidx);
    hipLaunchKernelGGL(merge_kernel, dim3(NB / 256), dim3(256), 0, stream, pvals, pidx, cand);
    hipLaunchKernelGGL(rerank_kernel, dim3(NB), dim3(64), 0, stream, proj, cand, widx, wts, cos_out);
    hipLaunchKernelGGL(out_kernel, dim3(NB), dim3(128), 0, stream, sess, widx, wts, out);
}

// Round 3
// 258.907 us; speedup vs baseline: 4.9831x; 1.8278x over previous
//
#include <hip/hip_runtime.h>
#include <hip/hip_bf16.h>
#include <math.h>

#define NB 8192
#define DD 512
#define HH 256
#define BM 128
#define BN 256
#define BK 32
#define KT (DD / BK)       // 16
#define NCT (NB / BN)      // 32 column groups
#define NCAND 8

typedef __attribute__((ext_vector_type(8))) short bf16x8;
typedef __attribute__((ext_vector_type(4))) float f32x4;

#define AS1(p) ((const __attribute__((address_space(1))) void*)(p))
#define AS3(p) ((__attribute__((address_space(3))) void*)(p))

// ---------------- Kernel 1: fused MLP  proj = relu(sess@W1+b1)@W2+b2 (+ bf16 copy) ----------------
__global__ __launch_bounds__(256)
void mlp_kernel(const float* __restrict__ sess, const float* __restrict__ W1,
                const float* __restrict__ b1, const float* __restrict__ W2,
                const float* __restrict__ b2, float* __restrict__ proj,
                __hip_bfloat16* __restrict__ projb) {
    __shared__ float srow[8][DD];   // 16 KB
    __shared__ float sh[8][HH];     // 8 KB
    const int t = threadIdx.x;      // 256
    const int r0 = blockIdx.x * 8;

    const float4* src = (const float4*)(sess + (size_t)r0 * DD);
    float4* dst = (float4*)&srow[0][0];
#pragma unroll
    for (int i = 0; i < 4; ++i) dst[t + i * 256] = src[t + i * 256];
    __syncthreads();

    float acc[8];
#pragma unroll
    for (int r = 0; r < 8; ++r) acc[r] = b1[t];
#pragma unroll 4
    for (int k = 0; k < DD; ++k) {
        float w = W1[k * HH + t];
#pragma unroll
        for (int r = 0; r < 8; ++r) acc[r] = fmaf(srow[r][k], w, acc[r]);
    }
#pragma unroll
    for (int r = 0; r < 8; ++r) sh[r][t] = fmaxf(acc[r], 0.f);
    __syncthreads();

    float a0[8], a1[8];
#pragma unroll
    for (int r = 0; r < 8; ++r) { a0[r] = b2[t]; a1[r] = b2[t + 256]; }
#pragma unroll 4
    for (int k = 0; k < HH; ++k) {
        float w0 = W2[k * DD + t];
        float w1 = W2[k * DD + t + 256];
#pragma unroll
        for (int r = 0; r < 8; ++r) {
            float hv = sh[r][k];
            a0[r] = fmaf(hv, w0, a0[r]);
            a1[r] = fmaf(hv, w1, a1[r]);
        }
    }
#pragma unroll
    for (int r = 0; r < 8; ++r) {
        size_t i0 = (size_t)(r0 + r) * DD + t;
        size_t i1 = i0 + 256;
        proj[i0] = a0[r];
        proj[i1] = a1[r];
        projb[i0] = __float2bfloat16(a0[r]);
        projb[i1] = __float2bfloat16(a1[r]);
    }
}

// merge two sorted-desc triples (values+indices) -> top-3 (value-only compare)
__device__ __forceinline__ void merge3(float& a0, float& a1, float& a2, int& x0, int& x1, int& x2,
                                       float b0, float b1, float b2, int y0, int y1, int y2) {
    bool c0 = a0 > b0;
    float r0 = c0 ? a0 : b0; int s0 = c0 ? x0 : y0;
    bool c1 = c0 ? (a1 > b0) : (a0 > b1);
    float r1 = c0 ? (c1 ? a1 : b0) : (c1 ? a0 : b1);
    int   s1 = c0 ? (c1 ? x1 : y0) : (c1 ? x0 : y1);
    int na = (int)c0 + (int)c1;
    float ca = (na == 2) ? a2 : ((na == 1) ? a1 : a0);
    int   cx = (na == 2) ? x2 : ((na == 1) ? x1 : x0);
    float cb = (na == 2) ? b0 : ((na == 1) ? b1 : b2);
    int   cy = (na == 2) ? y0 : ((na == 1) ? y1 : y2);
    bool c2 = ca > cb;
    a0 = r0; x0 = s0; a1 = r1; x1 = s1;
    a2 = c2 ? ca : cb; x2 = c2 ? cx : cy;
}

__device__ __forceinline__ void ins3(float v, int jg, float& v0, float& v1, float& v2,
                                     int& j0, int& j1, int& j2) {
    bool g2 = v > v2, g1 = v > v1, g0 = v > v0;
    float v2a = g2 ? v : v2; int j2a = g2 ? jg : j2;
    v2 = g1 ? v1 : v2a;      j2 = g1 ? j1 : j2a;
    float v1a = g1 ? v : v1; int j1a = g1 ? jg : j1;
    v1 = g0 ? v0 : v1a;      j1 = g0 ? j0 : j1a;
    v0 = g0 ? v : v0;        j0 = g0 ? jg : j0;
}

// ------------- Kernel 2: bf16 MFMA sim tile (128x256), dbuf pipeline, fused top-3 -------------
// grid (NB/BM=64, NCT=32), 256 thr = 4 waves (2x2 of 64x128), 16x16x32 bf16 MFMA.
__global__ __launch_bounds__(256)
void sim_mfma_kernel(const short* __restrict__ projb,
                     float* __restrict__ pvals, int* __restrict__ pidx) {
    __shared__ short smem[2 * BM * BK + 2 * BN * BK];   // 48 KB
    short* As = smem;                 // [2][BM*BK]
    short* Bs = smem + 2 * BM * BK;   // [2][BN*BK]
    unsigned long long* ev = (unsigned long long*)smem; // epilogue overlay [128][25] (stride 25)

    const int t = threadIdx.x;
    const int w = t >> 6, l = t & 63;
    const int wr = w >> 1, wc = w & 1;
    const int tx = l & 15, tg = l >> 4;
    const int rb = blockIdx.x * BM;
    const int jb = blockIdx.y * BN;

    // staging lane geometry (pre-swizzled global source; LDS dest linear = base + lane*16)
    const int rin = l >> 2;                         // row within 16-row chunk
    const int tgs = (l & 3) ^ ((rin >> 1) & 3);     // swizzled 16B-slot within the 64B row
    // ds_read lane offset (shorts), same swizzle on read side
    const int loff = tx * BK + ((tg ^ ((tx >> 1) & 3)) << 3);

    f32x4 acc[4][8];
#pragma unroll
    for (int i = 0; i < 4; ++i)
#pragma unroll
        for (int j = 0; j < 8; ++j) acc[i][j] = (f32x4){0.f, 0.f, 0.f, 0.f};

#define STAGE(buf, k0)                                                                      \
    {                                                                                       \
        _Pragma("unroll")                                                                   \
        for (int q = 0; q < 6; ++q) {                                                       \
            int c = w * 6 + q;                                                              \
            if (c < 8) {                                                                    \
                const short* g = projb + (size_t)(rb + c * 16 + rin) * DD + (k0) + tgs * 8; \
                __builtin_amdgcn_global_load_lds(AS1(g), AS3(As + (buf) * (BM * BK) + c * 512), 16, 0, 0); \
            } else {                                                                        \
                int cb = c - 8;                                                             \
                const short* g = projb + (size_t)(jb + cb * 16 + rin) * DD + (k0) + tgs * 8; \
                __builtin_amdgcn_global_load_lds(AS1(g), AS3(Bs + (buf) * (BN * BK) + cb * 512), 16, 0, 0); \
            }                                                                               \
        }                                                                                   \
    }

    STAGE(0, 0);
    __syncthreads();

    for (int kt = 0; kt < KT; ++kt) {
        if (kt + 1 < KT) STAGE((kt + 1) & 1, (kt + 1) * BK);
        const short* Ab = As + (kt & 1) * (BM * BK);
        const short* Bb = Bs + (kt & 1) * (BN * BK);
        bf16x8 af[4], bfr[8];
#pragma unroll
        for (int mi = 0; mi < 4; ++mi)
            af[mi] = *(const bf16x8*)&Ab[(wr * 64 + mi * 16) * BK + loff];
#pragma unroll
        for (int nj = 0; nj < 8; ++nj)
            bfr[nj] = *(const bf16x8*)&Bb[(wc * 128 + nj * 16) * BK + loff];
#pragma unroll
        for (int mi = 0; mi < 4; ++mi)
#pragma unroll
            for (int nj = 0; nj < 8; ++nj)
                acc[mi][nj] = __builtin_amdgcn_mfma_f32_16x16x32_bf16(af[mi], bfr[nj], acc[mi][nj], 0, 0, 0);
        __syncthreads();
    }
#undef STAGE

    // ---- epilogue: per-lane top3 over 8 cols, 2-step butterfly, LDS dump, per-row scan ----
#pragma unroll
    for (int mi = 0; mi < 4; ++mi) {
#pragma unroll
        for (int r = 0; r < 4; ++r) {
            float v0 = -INFINITY, v1 = -INFINITY, v2 = -INFINITY;
            int j0 = 0, j1 = 0, j2 = 0;
#pragma unroll
            for (int nj = 0; nj < 8; ++nj)
                ins3(acc[mi][nj][r], jb + wc * 128 + nj * 16 + tx, v0, v1, v2, j0, j1, j2);
#pragma unroll
            for (int s = 1; s <= 2; s <<= 1) {
                float b0v = __shfl_xor(v0, s, 64), b1v = __shfl_xor(v1, s, 64), b2v = __shfl_xor(v2, s, 64);
                int y0 = __shfl_xor(j0, s, 64), y1 = __shfl_xor(j1, s, 64), y2 = __shfl_xor(j2, s, 64);
                merge3(v0, v1, v2, j0, j1, j2, b0v, b1v, b2v, y0, y1, y2);
            }
            if ((tx & 3) == 0) {
                int lrow = wr * 64 + mi * 16 + tg * 4 + r;
                int slot = wc * 4 + (tx >> 2);
                unsigned long long* e = &ev[lrow * 25 + slot * 3];
                e[0] = ((unsigned long long)__float_as_uint(v0) << 32) | (unsigned)j0;
                e[1] = ((unsigned long long)__float_as_uint(v1) << 32) | (unsigned)j1;
                e[2] = ((unsigned long long)__float_as_uint(v2) << 32) | (unsigned)j2;
            }
        }
    }
    __syncthreads();
    if (t < BM) {
        float v0 = -INFINITY, v1 = -INFINITY, v2 = -INFINITY;
        int j0 = 0, j1 = 0, j2 = 0;
        const unsigned long long* e = &ev[t * 25];
#pragma unroll
        for (int s = 0; s < 24; ++s) {
            unsigned long long p = e[s];
            ins3(__uint_as_float((unsigned)(p >> 32)), (int)(unsigned)(p & 0xffffffffu),
                 v0, v1, v2, j0, j1, j2);
        }
        size_t base = ((size_t)(rb + t) * NCT + blockIdx.y) * 3;
        pvals[base + 0] = v0; pvals[base + 1] = v1; pvals[base + 2] = v2;
        pidx[base + 0] = j0; pidx[base + 1] = j1; pidx[base + 2] = j2;
    }
}

// ------------- Kernel 3: merge 32 partial top-3s -> top-8 candidate indices -------------
__global__ __launch_bounds__(256)
void merge_kernel(const float* __restrict__ pvals, const int* __restrict__ pidx,
                  int* __restrict__ cand) {
    int r = blockIdx.x * 256 + threadIdx.x;
    if (r >= NB) return;
    float bv[NCAND]; int bj[NCAND];
#pragma unroll
    for (int p = 0; p < NCAND; ++p) { bv[p] = -INFINITY; bj[p] = 0x7fffffff; }
    const float* pv = pvals + (size_t)r * NCT * 3;
    const int* pj = pidx + (size_t)r * NCT * 3;
    for (int s = 0; s < NCT * 3; ++s) {
        float v = pv[s]; int j = pj[s];
        if (!(v > bv[NCAND - 1])) continue;
#pragma unroll
        for (int p = NCAND - 1; p > 0; --p) {
            bool hp = v > bv[p];
            bool gp = v > bv[p - 1];
            bv[p] = hp ? (gp ? bv[p - 1] : v) : bv[p];
            bj[p] = hp ? (gp ? bj[p - 1] : j) : bj[p];
        }
        bool h0 = v > bv[0];
        bv[0] = h0 ? v : bv[0];
        bj[0] = h0 ? j : bj[0];
    }
    int* c = cand + (size_t)r * NCAND;
#pragma unroll
    for (int p = 0; p < NCAND; ++p) c[p] = bj[p];
}

// --------- Kernel 4: fused exact fp64 re-rank + softmax + gather + weighted sum ---------
__global__ __launch_bounds__(64)
void rerank_out_kernel(const float* __restrict__ proj, const int* __restrict__ cand,
                       const float* __restrict__ sess, float* __restrict__ out,
                       float* __restrict__ cos_out) {
    int r = blockIdx.x;
    int t = threadIdx.x;     // 64 lanes = 1 wave
    const float* pr = proj + (size_t)r * DD;
    int c[NCAND];
#pragma unroll
    for (int i = 0; i < NCAND; ++i) c[i] = cand[(size_t)r * NCAND + i];
    float myp[8];
#pragma unroll
    for (int k = 0; k < 8; ++k) myp[k] = pr[t * 8 + k];
    double part[NCAND];
#pragma unroll
    for (int i = 0; i < NCAND; ++i) {
        const float* pc = proj + (size_t)c[i] * DD;
        double s = 0.0;
#pragma unroll
        for (int k = 0; k < 8; ++k) s += (double)myp[k] * (double)pc[t * 8 + k];
        part[i] = s;
    }
#pragma unroll
    for (int i = 0; i < NCAND; ++i) {
#pragma unroll
        for (int s = 1; s < 64; s <<= 1) part[i] += __shfl_xor(part[i], s, 64);
    }
    // every lane computes the selection redundantly (identical fp64 inputs)
    double bv0 = -1e300, bv1 = -1e300, bv2 = -1e300;
    int bj0 = 0x7fffffff, bj1 = 0x7fffffff, bj2 = 0x7fffffff;
#pragma unroll
    for (int i = 0; i < NCAND; ++i) {
        double v = part[i]; int j = c[i];
        bool g2 = (v > bv2) || (v == bv2 && j < bj2);
        bool g1 = (v > bv1) || (v == bv1 && j < bj1);
        bool g0 = (v > bv0) || (v == bv0 && j < bj0);
        if (g2) {
            if (g1) {
                if (g0) { bv2 = bv1; bj2 = bj1; bv1 = bv0; bj1 = bj0; bv0 = v; bj0 = j; }
                else    { bv2 = bv1; bj2 = bj1; bv1 = v; bj1 = j; }
            } else      { bv2 = v; bj2 = j; }
        }
    }
    double e1 = exp(bv1 - bv0), e2 = exp(bv2 - bv0);
    double inv = 1.0 / (1.0 + e1 + e2);
    float w0 = (float)inv, w1 = (float)(e1 * inv), w2 = (float)(e2 * inv);
    if (t == 0) {
        cos_out[r * 3 + 0] = w0; cos_out[r * 3 + 1] = w1; cos_out[r * 3 + 2] = w2;
    }
    const float4* s0 = (const float4*)(sess + (size_t)bj0 * DD);
    const float4* s1 = (const float4*)(sess + (size_t)bj1 * DD);
    const float4* s2 = (const float4*)(sess + (size_t)bj2 * DD);
    float4* o = (float4*)(out + (size_t)r * 3 * DD);
    float4* nb = (float4*)(out + (size_t)NB * 3 * DD + (size_t)r * DD);
#pragma unroll
    for (int e = 0; e < 2; ++e) {
        int q = t + e * 64;          // float4 index 0..127
        float4 x0 = s0[q], x1 = s1[q], x2 = s2[q];
        o[q] = x0; o[128 + q] = x1; o[256 + q] = x2;
        float4 v;
        v.x = fmaf(w0, x0.x, fmaf(w1, x1.x, w2 * x2.x));
        v.y = fmaf(w0, x0.y, fmaf(w1, x1.y, w2 * x2.y));
        v.z = fmaf(w0, x0.z, fmaf(w1, x1.z, w2 * x2.z));
        v.w = fmaf(w0, x0.w, fmaf(w1, x1.w, w2 * x2.w));
        nb[q] = v;
    }
}

extern "C" void kernel_launch(void* const* d_in, const int* in_sizes, int n_in,
                              void* d_out, int out_size, void* d_ws, size_t ws_size,
                              hipStream_t stream) {
    const float* sess = (const float*)d_in[0];
    // d_in[1] = pool_emb: unused by the reference
    const float* W1 = (const float*)d_in[2];
    const float* b1 = (const float*)d_in[3];
    const float* W2 = (const float*)d_in[4];
    const float* b2 = (const float*)d_in[5];
    float* out = (float*)d_out;

    float* proj = (float*)d_ws;                                        // NB*DD f32
    __hip_bfloat16* projb = (__hip_bfloat16*)(proj + (size_t)NB * DD); // NB*DD bf16
    float* pvals = (float*)((char*)projb + (size_t)NB * DD * 2);       // NB*NCT*3 f32
    int*   pidx  = (int*)(pvals + (size_t)NB * NCT * 3);               // NB*NCT*3 i32
    int*   cand  = pidx + (size_t)NB * NCT * 3;                        // NB*NCAND i32

    float* cos_out = out + (size_t)NB * 3 * DD + (size_t)NB * DD;

    hipLaunchKernelGGL(mlp_kernel, dim3(NB / 8), dim3(256), 0, stream, sess, W1, b1, W2, b2, proj, projb);
    hipLaunchKernelGGL(sim_mfma_kernel, dim3(NB / BM, NCT), dim3(256), 0, stream, (const short*)projb, pvals, pidx);
    hipLaunchKernelGGL(merge_kernel, dim3(NB / 256), dim3(256), 0, stream, pvals, pidx, cand);
    hipLaunchKernelGGL(rerank_out_kernel, dim3(NB), dim3(64), 0, stream, proj, cand, sess, out, cos_out);
}

// Round 4
// 234.957 us; speedup vs baseline: 5.4911x; 1.1019x over previous
//
#include <hip/hip_runtime.h>
#include <hip/hip_bf16.h>
#include <math.h>

#define NB 8192
#define DD 512
#define HH 256
#define BM 128
#define BN 256
#define BK 32
#define KT (DD / BK)       // 16
#define NCT (NB / BN)      // 32 column groups
#define NCAND 8
#define MR 16              // mlp rows per block

typedef __attribute__((ext_vector_type(8))) short bf16x8;
typedef __attribute__((ext_vector_type(4))) float f32x4;

#define AS1(p) ((const __attribute__((address_space(1))) void*)(p))
#define AS3(p) ((__attribute__((address_space(3))) void*)(p))

// ---------------- Kernel 1: fused MLP (bit-exact fp32 chains, 16 rows/block) ----------------
__global__ __launch_bounds__(256)
void mlp_kernel(const float* __restrict__ sess, const float* __restrict__ W1,
                const float* __restrict__ b1, const float* __restrict__ W2,
                const float* __restrict__ b2, float* __restrict__ proj,
                __hip_bfloat16* __restrict__ projb) {
    __shared__ float srow[MR][DD];  // 32 KB
    __shared__ float sh[MR][HH];    // 16 KB
    const int t = threadIdx.x;      // 256
    const int r0 = blockIdx.x * MR;

    // stage MR input rows (coalesced float4): MR*DD/4 = 2048 float4, 8 per thread
    const float4* src = (const float4*)(sess + (size_t)r0 * DD);
    float4* dst = (float4*)&srow[0][0];
#pragma unroll
    for (int i = 0; i < (MR * DD / 4) / 256; ++i) dst[t + i * 256] = src[t + i * 256];
    __syncthreads();

    // layer 1: h[r][t], exact ascending-k fmaf chain per (r,t)
    float acc[MR];
#pragma unroll
    for (int r = 0; r < MR; ++r) acc[r] = b1[t];
    for (int k4 = 0; k4 < DD / 4; ++k4) {
        const int k = k4 * 4;
        float w0 = W1[(k + 0) * HH + t];
        float w1 = W1[(k + 1) * HH + t];
        float w2 = W1[(k + 2) * HH + t];
        float w3 = W1[(k + 3) * HH + t];
#pragma unroll
        for (int r = 0; r < MR; ++r) {
            float4 s4 = *(const float4*)&srow[r][k];
            acc[r] = fmaf(s4.x, w0, acc[r]);
            acc[r] = fmaf(s4.y, w1, acc[r]);
            acc[r] = fmaf(s4.z, w2, acc[r]);
            acc[r] = fmaf(s4.w, w3, acc[r]);
        }
    }
#pragma unroll
    for (int r = 0; r < MR; ++r) sh[r][t] = fmaxf(acc[r], 0.f);
    __syncthreads();

    // layer 2: proj[r][t] and proj[r][t+256], exact ascending-k chains
    float a0[MR], a1[MR];
#pragma unroll
    for (int r = 0; r < MR; ++r) { a0[r] = b2[t]; a1[r] = b2[t + 256]; }
    for (int k4 = 0; k4 < HH / 4; ++k4) {
        const int k = k4 * 4;
        float w0 = W2[(k + 0) * DD + t], u0 = W2[(k + 0) * DD + t + 256];
        float w1 = W2[(k + 1) * DD + t], u1 = W2[(k + 1) * DD + t + 256];
        float w2 = W2[(k + 2) * DD + t], u2 = W2[(k + 2) * DD + t + 256];
        float w3 = W2[(k + 3) * DD + t], u3 = W2[(k + 3) * DD + t + 256];
#pragma unroll
        for (int r = 0; r < MR; ++r) {
            float4 h4 = *(const float4*)&sh[r][k];
            a0[r] = fmaf(h4.x, w0, a0[r]); a1[r] = fmaf(h4.x, u0, a1[r]);
            a0[r] = fmaf(h4.y, w1, a0[r]); a1[r] = fmaf(h4.y, u1, a1[r]);
            a0[r] = fmaf(h4.z, w2, a0[r]); a1[r] = fmaf(h4.z, u2, a1[r]);
            a0[r] = fmaf(h4.w, w3, a0[r]); a1[r] = fmaf(h4.w, u3, a1[r]);
        }
    }
#pragma unroll
    for (int r = 0; r < MR; ++r) {
        size_t i0 = (size_t)(r0 + r) * DD + t;
        size_t i1 = i0 + 256;
        proj[i0] = a0[r];
        proj[i1] = a1[r];
        projb[i0] = __float2bfloat16(a0[r]);
        projb[i1] = __float2bfloat16(a1[r]);
    }
}

// merge two sorted-desc triples -> top-3 (value-only compare)
__device__ __forceinline__ void merge3(float& a0, float& a1, float& a2, int& x0, int& x1, int& x2,
                                       float b0, float b1, float b2, int y0, int y1, int y2) {
    bool c0 = a0 > b0;
    float r0 = c0 ? a0 : b0; int s0 = c0 ? x0 : y0;
    bool c1 = c0 ? (a1 > b0) : (a0 > b1);
    float r1 = c0 ? (c1 ? a1 : b0) : (c1 ? a0 : b1);
    int   s1 = c0 ? (c1 ? x1 : y0) : (c1 ? x0 : y1);
    int na = (int)c0 + (int)c1;
    float ca = (na == 2) ? a2 : ((na == 1) ? a1 : a0);
    int   cx = (na == 2) ? x2 : ((na == 1) ? x1 : x0);
    float cb = (na == 2) ? b0 : ((na == 1) ? b1 : b2);
    int   cy = (na == 2) ? y0 : ((na == 1) ? y1 : y2);
    bool c2 = ca > cb;
    a0 = r0; x0 = s0; a1 = r1; x1 = s1;
    a2 = c2 ? ca : cb; x2 = c2 ? cx : cy;
}

__device__ __forceinline__ void ins3(float v, int jg, float& v0, float& v1, float& v2,
                                     int& j0, int& j1, int& j2) {
    bool g2 = v > v2, g1 = v > v1, g0 = v > v0;
    float v2a = g2 ? v : v2; int j2a = g2 ? jg : j2;
    v2 = g1 ? v1 : v2a;      j2 = g1 ? j1 : j2a;
    float v1a = g1 ? v : v1; int j1a = g1 ? jg : j1;
    v1 = g0 ? v0 : v1a;      j1 = g0 ? j0 : j1a;
    v0 = g0 ? v : v0;        j0 = g0 ? jg : j0;
}

// ------------- Kernel 2: bf16 MFMA sim (128x256), counted-vmcnt dbuf, fused top-3 -------------
__global__ __launch_bounds__(256)
void sim_mfma_kernel(const short* __restrict__ projb,
                     float* __restrict__ pvals, int* __restrict__ pidx) {
    __shared__ short smem[2 * BM * BK + 2 * BN * BK];   // 48 KB
    short* As = smem;                 // [2][BM*BK]
    short* Bs = smem + 2 * BM * BK;   // [2][BN*BK]
    unsigned long long* ev = (unsigned long long*)smem; // epilogue overlay [128][25]

    const int t = threadIdx.x;
    const int w = t >> 6, l = t & 63;
    const int wr = w >> 1, wc = w & 1;
    const int tx = l & 15, tg = l >> 4;
    const int rb = blockIdx.x * BM;
    const int jb = blockIdx.y * BN;

    const int rin = l >> 2;                         // row within 16-row chunk
    const int tgs = (l & 3) ^ ((rin >> 1) & 3);     // pre-swizzled 16B-slot in 64B row
    const int loff = tx * BK + ((tg ^ ((tx >> 1) & 3)) << 3);  // swizzled read offset

    f32x4 acc[4][8];
#pragma unroll
    for (int i = 0; i < 4; ++i)
#pragma unroll
        for (int j = 0; j < 8; ++j) acc[i][j] = (f32x4){0.f, 0.f, 0.f, 0.f};

#define STAGE(buf, k0)                                                                      \
    {                                                                                       \
        _Pragma("unroll")                                                                   \
        for (int q = 0; q < 6; ++q) {                                                       \
            int c = w * 6 + q;                                                              \
            if (c < 8) {                                                                    \
                const short* g = projb + (size_t)(rb + c * 16 + rin) * DD + (k0) + tgs * 8; \
                __builtin_amdgcn_global_load_lds(AS1(g), AS3(As + (buf) * (BM * BK) + c * 512), 16, 0, 0); \
            } else {                                                                        \
                int cb = c - 8;                                                             \
                const short* g = projb + (size_t)(jb + cb * 16 + rin) * DD + (k0) + tgs * 8; \
                __builtin_amdgcn_global_load_lds(AS1(g), AS3(Bs + (buf) * (BN * BK) + cb * 512), 16, 0, 0); \
            }                                                                               \
        }                                                                                   \
    }

#define COMPUTE(kt)                                                                          \
    {                                                                                        \
        const short* Ab = As + ((kt) & 1) * (BM * BK);                                       \
        const short* Bb = Bs + ((kt) & 1) * (BN * BK);                                       \
        bf16x8 af[4], bfr[8];                                                                \
        _Pragma("unroll")                                                                    \
        for (int mi = 0; mi < 4; ++mi)                                                       \
            af[mi] = *(const bf16x8*)&Ab[(wr * 64 + mi * 16) * BK + loff];                   \
        _Pragma("unroll")                                                                    \
        for (int nj = 0; nj < 8; ++nj)                                                       \
            bfr[nj] = *(const bf16x8*)&Bb[(wc * 128 + nj * 16) * BK + loff];                 \
        asm volatile("s_waitcnt lgkmcnt(0)" ::: "memory");                                   \
        __builtin_amdgcn_sched_barrier(0);                                                   \
        __builtin_amdgcn_s_barrier();   /* barrier2: reads done, next STAGE may overwrite */ \
        __builtin_amdgcn_sched_barrier(0);                                                   \
        _Pragma("unroll")                                                                    \
        for (int mi = 0; mi < 4; ++mi)                                                       \
            _Pragma("unroll")                                                                \
            for (int nj = 0; nj < 8; ++nj)                                                   \
                acc[mi][nj] = __builtin_amdgcn_mfma_f32_16x16x32_bf16(af[mi], bfr[nj], acc[mi][nj], 0, 0, 0); \
    }

    STAGE(0, 0);
    for (int kt = 0; kt < KT - 1; ++kt) {
        STAGE((kt + 1) & 1, (kt + 1) * BK);
        // wait own 6 older loads (current buffer) done, then sync all waves
        asm volatile("s_waitcnt vmcnt(6)" ::: "memory");
        __builtin_amdgcn_sched_barrier(0);
        __builtin_amdgcn_s_barrier();   // barrier1: current buffer fully staged
        __builtin_amdgcn_sched_barrier(0);
        COMPUTE(kt);
    }
    // peeled last iteration
    asm volatile("s_waitcnt vmcnt(0)" ::: "memory");
    __builtin_amdgcn_sched_barrier(0);
    __builtin_amdgcn_s_barrier();
    __builtin_amdgcn_sched_barrier(0);
    COMPUTE(KT - 1);
#undef STAGE
#undef COMPUTE

    __syncthreads();   // all waves done with LDS tiles before ev overlay

    // ---- epilogue: per-lane top3 over 8 cols, 2-step butterfly, LDS dump, per-row scan ----
#pragma unroll
    for (int mi = 0; mi < 4; ++mi) {
#pragma unroll
        for (int r = 0; r < 4; ++r) {
            float v0 = -INFINITY, v1 = -INFINITY, v2 = -INFINITY;
            int j0 = 0, j1 = 0, j2 = 0;
#pragma unroll
            for (int nj = 0; nj < 8; ++nj)
                ins3(acc[mi][nj][r], jb + wc * 128 + nj * 16 + tx, v0, v1, v2, j0, j1, j2);
#pragma unroll
            for (int s = 1; s <= 2; s <<= 1) {
                float b0v = __shfl_xor(v0, s, 64), b1v = __shfl_xor(v1, s, 64), b2v = __shfl_xor(v2, s, 64);
                int y0 = __shfl_xor(j0, s, 64), y1 = __shfl_xor(j1, s, 64), y2 = __shfl_xor(j2, s, 64);
                merge3(v0, v1, v2, j0, j1, j2, b0v, b1v, b2v, y0, y1, y2);
            }
            if ((tx & 3) == 0) {
                int lrow = wr * 64 + mi * 16 + tg * 4 + r;
                int slot = wc * 4 + (tx >> 2);
                unsigned long long* e = &ev[lrow * 25 + slot * 3];
                e[0] = ((unsigned long long)__float_as_uint(v0) << 32) | (unsigned)j0;
                e[1] = ((unsigned long long)__float_as_uint(v1) << 32) | (unsigned)j1;
                e[2] = ((unsigned long long)__float_as_uint(v2) << 32) | (unsigned)j2;
            }
        }
    }
    __syncthreads();
    if (t < BM) {
        float v0 = -INFINITY, v1 = -INFINITY, v2 = -INFINITY;
        int j0 = 0, j1 = 0, j2 = 0;
        const unsigned long long* e = &ev[t * 25];
#pragma unroll
        for (int s = 0; s < 24; ++s) {
            unsigned long long p = e[s];
            ins3(__uint_as_float((unsigned)(p >> 32)), (int)(unsigned)(p & 0xffffffffu),
                 v0, v1, v2, j0, j1, j2);
        }
        size_t base = ((size_t)(rb + t) * NCT + blockIdx.y) * 3;
        pvals[base + 0] = v0; pvals[base + 1] = v1; pvals[base + 2] = v2;
        pidx[base + 0] = j0; pidx[base + 1] = j1; pidx[base + 2] = j2;
    }
}

// --- Kernel 3: fused merge(top-8) + exact fp64 re-rank + softmax + gather + weighted sum ---
__global__ __launch_bounds__(64)
void rerank_out_kernel(const float* __restrict__ proj, const float* __restrict__ pvals,
                       const int* __restrict__ pidx, const float* __restrict__ sess,
                       float* __restrict__ out, float* __restrict__ cos_out) {
    int r = blockIdx.x;
    int t = threadIdx.x;     // 64 lanes = 1 wave
    // all-lane redundant top-8 scan (identical insertion order to old merge_kernel)
    float bv[NCAND]; int bj[NCAND];
#pragma unroll
    for (int p = 0; p < NCAND; ++p) { bv[p] = -INFINITY; bj[p] = 0x7fffffff; }
    const float* pv = pvals + (size_t)r * NCT * 3;
    const int* pj = pidx + (size_t)r * NCT * 3;
    for (int s = 0; s < NCT * 3; ++s) {
        float v = pv[s]; int j = pj[s];
        if (!(v > bv[NCAND - 1])) continue;
#pragma unroll
        for (int p = NCAND - 1; p > 0; --p) {
            bool hp = v > bv[p];
            bool gp = v > bv[p - 1];
            bv[p] = hp ? (gp ? bv[p - 1] : v) : bv[p];
            bj[p] = hp ? (gp ? bj[p - 1] : j) : bj[p];
        }
        bool h0 = v > bv[0];
        bv[0] = h0 ? v : bv[0];
        bj[0] = h0 ? j : bj[0];
    }

    const float* pr = proj + (size_t)r * DD;
    float myp[8];
#pragma unroll
    for (int k = 0; k < 8; ++k) myp[k] = pr[t * 8 + k];
    double part[NCAND];
#pragma unroll
    for (int i = 0; i < NCAND; ++i) {
        const float* pc = proj + (size_t)bj[i] * DD;
        double s = 0.0;
#pragma unroll
        for (int k = 0; k < 8; ++k) s += (double)myp[k] * (double)pc[t * 8 + k];
        part[i] = s;
    }
#pragma unroll
    for (int i = 0; i < NCAND; ++i) {
#pragma unroll
        for (int s = 1; s < 64; s <<= 1) part[i] += __shfl_xor(part[i], s, 64);
    }
    // every lane computes the selection redundantly (identical fp64 inputs)
    double bv0 = -1e300, bv1 = -1e300, bv2 = -1e300;
    int bj0 = 0x7fffffff, bj1 = 0x7fffffff, bj2 = 0x7fffffff;
#pragma unroll
    for (int i = 0; i < NCAND; ++i) {
        double v = part[i]; int j = bj[i];
        bool g2 = (v > bv2) || (v == bv2 && j < bj2);
        bool g1 = (v > bv1) || (v == bv1 && j < bj1);
        bool g0 = (v > bv0) || (v == bv0 && j < bj0);
        if (g2) {
            if (g1) {
                if (g0) { bv2 = bv1; bj2 = bj1; bv1 = bv0; bj1 = bj0; bv0 = v; bj0 = j; }
                else    { bv2 = bv1; bj2 = bj1; bv1 = v; bj1 = j; }
            } else      { bv2 = v; bj2 = j; }
        }
    }
    double e1 = exp(bv1 - bv0), e2 = exp(bv2 - bv0);
    double inv = 1.0 / (1.0 + e1 + e2);
    float w0 = (float)inv, w1 = (float)(e1 * inv), w2 = (float)(e2 * inv);
    if (t == 0) {
        cos_out[r * 3 + 0] = w0; cos_out[r * 3 + 1] = w1; cos_out[r * 3 + 2] = w2;
    }
    const float4* s0 = (const float4*)(sess + (size_t)bj0 * DD);
    const float4* s1 = (const float4*)(sess + (size_t)bj1 * DD);
    const float4* s2 = (const float4*)(sess + (size_t)bj2 * DD);
    float4* o = (float4*)(out + (size_t)r * 3 * DD);
    float4* nb = (float4*)(out + (size_t)NB * 3 * DD + (size_t)r * DD);
#pragma unroll
    for (int e = 0; e < 2; ++e) {
        int q = t + e * 64;          // float4 index 0..127
        float4 x0 = s0[q], x1 = s1[q], x2 = s2[q];
        o[q] = x0; o[128 + q] = x1; o[256 + q] = x2;
        float4 v;
        v.x = fmaf(w0, x0.x, fmaf(w1, x1.x, w2 * x2.x));
        v.y = fmaf(w0, x0.y, fmaf(w1, x1.y, w2 * x2.y));
        v.z = fmaf(w0, x0.z, fmaf(w1, x1.z, w2 * x2.z));
        v.w = fmaf(w0, x0.w, fmaf(w1, x1.w, w2 * x2.w));
        nb[q] = v;
    }
}

extern "C" void kernel_launch(void* const* d_in, const int* in_sizes, int n_in,
                              void* d_out, int out_size, void* d_ws, size_t ws_size,
                              hipStream_t stream) {
    const float* sess = (const float*)d_in[0];
    // d_in[1] = pool_emb: unused by the reference
    const float* W1 = (const float*)d_in[2];
    const float* b1 = (const float*)d_in[3];
    const float* W2 = (const float*)d_in[4];
    const float* b2 = (const float*)d_in[5];
    float* out = (float*)d_out;

    float* proj = (float*)d_ws;                                        // NB*DD f32
    __hip_bfloat16* projb = (__hip_bfloat16*)(proj + (size_t)NB * DD); // NB*DD bf16
    float* pvals = (float*)((char*)projb + (size_t)NB * DD * 2);       // NB*NCT*3 f32
    int*   pidx  = (int*)(pvals + (size_t)NB * NCT * 3);               // NB*NCT*3 i32

    float* cos_out = out + (size_t)NB * 3 * DD + (size_t)NB * DD;

    hipLaunchKernelGGL(mlp_kernel, dim3(NB / MR), dim3(256), 0, stream, sess, W1, b1, W2, b2, proj, projb);
    hipLaunchKernelGGL(sim_mfma_kernel, dim3(NB / BM, NCT), dim3(256), 0, stream, (const short*)projb, pvals, pidx);
    hipLaunchKernelGGL(rerank_out_kernel, dim3(NB), dim3(64), 0, stream, proj, pvals, pidx, sess, out, cos_out);
}